// Round 14
// baseline (7068.278 us; speedup 1.0000x reference)
//
#include <hip/hip_runtime.h>

typedef unsigned int u32;
typedef unsigned long long u64;
typedef float f32x2 __attribute__((ext_vector_type(2)));
typedef float f32x4 __attribute__((ext_vector_type(4)));

#define N_PTS 16384
#define N_S   8192
#define NB    10
#define CHID  64
#define COUT  128
#define R2    0.0625f
#define NCELL 4096

// ======================= sort: morton counting sort =======================
__device__ __forceinline__ u32 spread3(u32 v) {  // 4 bits -> every 3rd bit
  return (v & 1u) | ((v & 2u) << 2) | ((v & 4u) << 4) | ((v & 8u) << 6);
}

__global__ void cell_kernel(const float* __restrict__ pos, int* __restrict__ cellid,
                            int* __restrict__ hist) {
  int i = blockIdx.x * 256 + threadIdx.x;
  float x = pos[3 * i], y = pos[3 * i + 1], z = pos[3 * i + 2];
  u32 ix = (u32)(x * 16.0f); if (ix > 15u) ix = 15u;
  u32 iy = (u32)(y * 16.0f); if (iy > 15u) iy = 15u;
  u32 iz = (u32)(z * 16.0f); if (iz > 15u) iz = 15u;
  u32 c = spread3(ix) | (spread3(iy) << 1) | (spread3(iz) << 2);
  cellid[i] = (int)c;
  atomicAdd(&hist[c], 1);
}

__global__ __launch_bounds__(1024) void scan_kernel(const int* __restrict__ hist,
                                                    int* __restrict__ base) {
  __shared__ int sp[1024];
  int t = threadIdx.x;
  int h0 = hist[4 * t], h1 = hist[4 * t + 1], h2 = hist[4 * t + 2], h3 = hist[4 * t + 3];
  int s = h0 + h1 + h2 + h3;
  int acc = s;
  sp[t] = s;
  __syncthreads();
  for (int off = 1; off < 1024; off <<= 1) {
    int v = (t >= off) ? sp[t - off] : 0;
    __syncthreads();
    acc += v;
    sp[t] = acc;
    __syncthreads();
  }
  int excl = acc - s;
  base[4 * t + 0] = excl;
  base[4 * t + 1] = excl + h0;
  base[4 * t + 2] = excl + h0 + h1;
  base[4 * t + 3] = excl + h0 + h1 + h2;
}

__global__ void scatter_kernel(const float* __restrict__ pos, const int* __restrict__ cellid,
                               int* __restrict__ base, float* __restrict__ xs,
                               float* __restrict__ ys, float* __restrict__ zs,
                               int* __restrict__ oid) {
  int i = blockIdx.x * 256 + threadIdx.x;
  int c = cellid[i];
  int d = atomicAdd(&base[c], 1);
  xs[d] = pos[3 * i]; ys[d] = pos[3 * i + 1]; zs[d] = pos[3 * i + 2];
  oid[d] = i;
}

// ======================= fused FPS + kNN + MLP =======================
// R28 post-mortem: relaxed polls killed the buffer_inv storm (9050 -> 6870us
// fused; total 6900, past the unfused 7190 best). Residual: fps-in-fusion
// ~6840 vs 6590 standalone (+250us). fps's CU is exclusive -> contention is
// memory-system only: (1) ~24 worker blocks stream pos tiles / out writes
// through fps's XCD L2, capacity-evicting fps's hot xs lines (critical-chain
// load degrades L2-hit ~200cy -> L3 ~500cy); (2) fps's RELEASE wbl2 (1/32
// iters) writes back ALL dirty lines on its XCD's L2 incl. co-resident
// workers' out/src lines.
// R29 (resubmit; R13 was a compile error: __builtin_nontemporal_store needs
// a clang ext_vector_type, not HIP's float4 class -> f32x4 alias):
// (a) ALL worker pos reads + out/tail-zero writes become NON-TEMPORAL
// (cache hint only; values identical; workers are latency-tolerant);
// (b) fps's idx publishes become agent-scope RELAXED ATOMIC STORES -> land
// at the L3 coherence point, never dirty in L2 -> wbl2 payload ~empty. The
// RELEASE's vmcnt wait still orders idx stores before prog. Protocol
// otherwise identical to R28 (passed).
#define FPS_T 1024
#define PPT   16
#define WRK   192          // worker blocks
#define NCHK  (N_S / 32)   // 256 chunks

// LDS union layout (bytes):
//  fps   : s_yz [0,131072) | s_k [131072,131328)
//  worker: s_p [0,16384) | spd [16384,57472) | spi [57472,98560)
//          | sW2T [98560,133376) | sW1 [133376,134144) | sb1 [134144,134400)
//          | sprog [134400,134404)
//  mlp scratch aliases spd (msh1) and spi (msrel) after merge completes.
#define OFF_SK   131072
#define OFF_SPD  16384
#define OFF_SPI  57472
#define OFF_W2T  98560
#define OFF_W1   133376
#define OFF_B1   134144
#define OFF_PROG 134400
#define SMEM_SZ  134432

#define KNS    32
#define KTILE  1024
#define KPAD   321   // KNS*NB=320 -> pad to 321 (==1 mod 32, conflict-free)
#define W2S    68    // W2T stride: 16B-aligned (68*4=272=17*16), bank-swept

#define PT_LIST(OP) OP(0) OP(1) OP(2) OP(3) OP(4) OP(5) OP(6) OP(7) \
                    OP(8) OP(9) OP(10) OP(11) OP(12) OP(13) OP(14) OP(15)
#define G4_LIST(OP) OP(0,0,1,2,3,0,1)   OP(1,4,5,6,7,2,3) \
                    OP(2,8,9,10,11,4,5) OP(3,12,13,14,15,6,7)
#define PR_LIST(OP) OP(0) OP(1) OP(2) OP(3) OP(4) OP(5) OP(6) OP(7)

// u64 max via positive-double max (key high word = finite positive float bits
// -> double exponent never all-ones, sign 0; positive doubles order == bit order).
__device__ __forceinline__ u64 u64fmax(u64 a, u64 b) {
  double ad = __longlong_as_double((long long)a);
  double bd = __longlong_as_double((long long)b);
  return (u64)(long long)__double_as_longlong(fmax(ad, bd));
}

template <int CTRL, int RM>
__device__ __forceinline__ u64 dppmax(u64 cur) {
  int slo = __builtin_amdgcn_update_dpp(0, (int)(u32)cur, CTRL, RM, 0xf, false);
  int shi = __builtin_amdgcn_update_dpp(0, (int)(u32)(cur >> 32), CTRL, RM, 0xf, false);
  u64 o = ((u64)(u32)shi << 32) | (u32)slo;
  return u64fmax(o, cur);
}

// packed 2xf32 ops (VOP3P). IEEE RNE per element, no contraction (opaque asm).
__device__ __forceinline__ f32x2 pk_add(f32x2 a, f32x2 b) {
  f32x2 d;
  asm("v_pk_add_f32 %0, %1, %2" : "=v"(d) : "v"(a), "v"(b));
  return d;
}
__device__ __forceinline__ f32x2 pk_mul(f32x2 a, f32x2 b) {
  f32x2 d;
  asm("v_pk_mul_f32 %0, %1, %2" : "=v"(d) : "v"(a), "v"(b));
  return d;
}

__global__ __launch_bounds__(1024, 4)
void fused_kernel(const float* __restrict__ pos,
                  const float* __restrict__ xs,
                  const float* __restrict__ ys,
                  const float* __restrict__ zs,
                  const int* __restrict__ oidv,
                  int* __restrict__ idx,
                  int* __restrict__ src,
                  int* __restrict__ valid,
                  const float* __restrict__ W1,
                  const float* __restrict__ b1,
                  const float* __restrict__ W2,
                  const float* __restrict__ b2,
                  float* __restrict__ out,
                  int* __restrict__ prog) {
  __shared__ __align__(16) unsigned char smem[SMEM_SZ];
  const int t = threadIdx.x;

  if (blockIdx.x == 0) {
    // =================== FPS (R24 body, frozen; + prog publish) ===================
    float2* s_yz = (float2*)smem;
    u64 (*s_k)[16] = (u64 (*)[16])(smem + OFF_SK);
    const int wv = t >> 6;
    const int base0 = t * PPT;
    const float4* __restrict__ xv = (const float4*)(xs + base0);
    const float4* __restrict__ yv = (const float4*)(ys + base0);
    const float4* __restrict__ zv = (const float4*)(zs + base0);
    const int4*   __restrict__ ov = (const int4*)(oidv + base0);

#define DECLP(J) float md##J;
    PT_LIST(DECLP)
#undef DECLP
#define DECLC(J) u32 C##J;
    PT_LIST(DECLC)
#undef DECLC
#define DECLX(P) f32x2 X##P; f32x2 Y##P; f32x2 Z##P;
    PR_LIST(DECLX)
#undef DECLX

    float bnx = 3.4e38f, bxx = -3.4e38f, bny = 3.4e38f, bxy = -3.4e38f,
          bnz = 3.4e38f, bxz = -3.4e38f;

#define INIT4(G, J0, J1, J2, J3, PA, PB) { \
    float4 vx = xv[G], vy = yv[G], vz = zv[G]; int4 vo = ov[G]; \
    md##J0 = 3.402823466e38f; md##J1 = 3.402823466e38f; \
    md##J2 = 3.402823466e38f; md##J3 = 3.402823466e38f; \
    X##PA.x = vx.x; X##PA.y = vx.y; X##PB.x = vx.z; X##PB.y = vx.w; \
    Y##PA.x = vy.x; Y##PA.y = vy.y; Y##PB.x = vy.z; Y##PB.y = vy.w; \
    Z##PA.x = vz.x; Z##PA.y = vz.y; Z##PB.x = vz.z; Z##PB.y = vz.w; \
    s_yz[J0 * FPS_T + t] = make_float2(vy.x, vz.x); \
    s_yz[J1 * FPS_T + t] = make_float2(vy.y, vz.y); \
    s_yz[J2 * FPS_T + t] = make_float2(vy.z, vz.z); \
    s_yz[J3 * FPS_T + t] = make_float2(vy.w, vz.w); \
    C##J0 = ((16383u - (u32)vo.x) << 14) | (u32)(base0 + J0); \
    C##J1 = ((16383u - (u32)vo.y) << 14) | (u32)(base0 + J1); \
    C##J2 = ((16383u - (u32)vo.z) << 14) | (u32)(base0 + J2); \
    C##J3 = ((16383u - (u32)vo.w) << 14) | (u32)(base0 + J3); \
    bnx = fminf(bnx, fminf(fminf(vx.x, vx.y), fminf(vx.z, vx.w))); \
    bxx = fmaxf(bxx, fmaxf(fmaxf(vx.x, vx.y), fmaxf(vx.z, vx.w))); \
    bny = fminf(bny, fminf(fminf(vy.x, vy.y), fminf(vy.z, vy.w))); \
    bxy = fmaxf(bxy, fmaxf(fmaxf(vy.x, vy.y), fmaxf(vy.z, vy.w))); \
    bnz = fminf(bnz, fminf(fminf(vz.x, vz.y), fminf(vz.z, vz.w))); \
    bxz = fmaxf(bxz, fmaxf(fmaxf(vz.x, vz.y), fmaxf(vz.z, vz.w))); }
    G4_LIST(INIT4)
#undef INIT4

    // key = md_bits<<32 | (16383-oid)<<14 | sidx. Lex max == numpy argmax.
    u64 ckey = 0;
    u64 wklast = 0;
    float cmaxf = 3.402823466e38f;
    float cx = pos[0], cy = pos[1], cz = pos[2];
    // idx published via agent-scope atomic stores: land at L3 directly, never
    // dirty in L2 -> the release's wbl2 payload stays ~empty.
    if (t == 0) __hip_atomic_store(idx, 0, __ATOMIC_RELAXED, __HIP_MEMORY_SCOPE_AGENT);
    __syncthreads();

    for (int k = 0; k < N_S - 1; ++k) {
      float dxl = fmaxf(fmaxf(bnx - cx, cx - bxx), 0.0f);
      float dyl = fmaxf(fmaxf(bny - cy, cy - bxy), 0.0f);
      float dzl = fmaxf(fmaxf(bnz - cz, cz - bxz), 0.0f);
      float lb2 = dxl * dxl + dyl * dyl + dzl * dzl;
      bool act = (0.99f * lb2 < cmaxf);

      if (__ballot(act)) {
        if (act) {
          f32x2 ncx2; ncx2.x = -cx; ncx2.y = -cx;
          f32x2 ncy2; ncy2.x = -cy; ncy2.y = -cy;
          f32x2 ncz2; ncz2.x = -cz; ncz2.y = -cz;
          u64 bkA = 0, bkB = 0;
#define UPDP(P, J0, J1) { \
          f32x2 dx2 = pk_add(X##P, ncx2); \
          f32x2 dy2 = pk_add(Y##P, ncy2); \
          f32x2 dz2 = pk_add(Z##P, ncz2); \
          f32x2 sq = pk_add(pk_mul(dx2, dx2), pk_mul(dy2, dy2)); \
          f32x2 d2 = pk_add(sq, pk_mul(dz2, dz2)); \
          float m0 = fminf(md##J0, d2.x); md##J0 = m0; \
          bkA = u64fmax(bkA, ((u64)__float_as_uint(m0) << 32) | C##J0); \
          float m1 = fminf(md##J1, d2.y); md##J1 = m1; \
          bkB = u64fmax(bkB, ((u64)__float_as_uint(m1) << 32) | C##J1); }
          UPDP(0, 0, 1)  UPDP(1, 2, 3)  UPDP(2, 4, 5)  UPDP(3, 6, 7)
          UPDP(4, 8, 9)  UPDP(5, 10, 11) UPDP(6, 12, 13) UPDP(7, 14, 15)
#undef UPDP
          ckey = u64fmax(bkA, bkB);
          cmaxf = __uint_as_float((u32)(ckey >> 32));
        }
        u64 wk = ckey;
        wk = dppmax<0x111, 0xf>(wk);   // row_shr:1
        wk = dppmax<0x112, 0xf>(wk);   // row_shr:2
        wk = dppmax<0x114, 0xf>(wk);   // row_shr:4
        wk = dppmax<0x118, 0xf>(wk);   // row_shr:8
        wk = dppmax<0x142, 0xa>(wk);   // row_bcast:15 -> rows 1,3
        wk = dppmax<0x143, 0xc>(wk);   // row_bcast:31 -> rows 2,3
        wklast = wk;
      }
      if ((t & 63) == 63) s_k[k & 1][wv] = wklast;
      __syncthreads();

      u64 gk = s_k[k & 1][t & 15];
      gk = dppmax<0x121, 0xf>(gk);   // row_ror:1
      gk = dppmax<0x122, 0xf>(gk);   // row_ror:2
      gk = dppmax<0x124, 0xf>(gk);   // row_ror:4
      gk = dppmax<0x128, 0xf>(gk);   // row_ror:8
      u32 glo = (u32)__builtin_amdgcn_readfirstlane((int)(u32)gk);
      u32 ghi = (u32)__builtin_amdgcn_readfirstlane((int)(u32)(gk >> 32));
      u64 gmax = ((u64)ghi << 32) | glo;
      int sidx = (int)(gmax & 16383u);
      if (t == 0) {
        __hip_atomic_store(idx + k + 1, 16383 - (int)((gmax >> 14) & 16383u),
                           __ATOMIC_RELAXED, __HIP_MEMORY_SCOPE_AGENT);
        // publish at chunk boundaries: RELEASE's vmcnt wait orders the idx
        // atomic stores (already headed to L3) before the counter store.
        if ((k & 31) == 30)
          __hip_atomic_store(prog, k + 2, __ATOMIC_RELEASE, __HIP_MEMORY_SCOPE_AGENT);
      }
      int cell = (sidx & (PPT - 1)) * FPS_T + (sidx >> 4);
      cx = xs[sidx];
      float2 yz = s_yz[cell];
      cy = yz.x;
      cz = yz.y;
    }
  } else {
    // =================== worker: kNN + MLP per ready chunk ===================
    const int wid = blockIdx.x - 1;   // 0..WRK-1
    float4* s_p = (float4*)smem;
    float (*spd)[KPAD] = (float (*)[KPAD])(smem + OFF_SPD);
    int   (*spi)[KPAD] = (int (*)[KPAD])(smem + OFF_SPI);
    float* sW2T = (float*)(smem + OFF_W2T);
    float* sW1  = (float*)(smem + OFF_W1);
    float* sb1  = (float*)(smem + OFF_B1);
    int*   sprog = (int*)(smem + OFF_PROG);
    float* msh1  = (float*)(smem + OFF_SPD);   // [8][NB][CHID], after merge
    float* msrel = (float*)(smem + OFF_SPI);   // [8][NB][3], after merge

    // stage W2 transposed (stride W2S) + W1 + b1; zero a tail-row slice.
    // All overlapped with fps (no dependency yet). Tail zeros are
    // NON-TEMPORAL: write-only stream, keep it out of the L2s.
    for (int e = t; e < CHID * COUT; e += 1024) {
      int kk = e >> 7, c = e & (COUT - 1);
      sW2T[c * W2S + kk] = W2[e];
    }
    if (t < 3 * CHID) sW1[t] = W1[t];
    if (t < CHID) sb1[t] = b1[t];
    {
      f32x4* outv = (f32x4*)(out + (size_t)N_S * COUT);
      const int cnt = (N_PTS - N_S) * COUT / 4;
      f32x4 z4;
      z4.x = 0.f; z4.y = 0.f; z4.z = 0.f; z4.w = 0.f;
      for (int j = wid * 1024 + t; j < cnt; j += WRK * 1024)
        __builtin_nontemporal_store(z4, &outv[j]);
    }
    __syncthreads();

    for (int gc = wid; gc < NCHK; gc += WRK) {
      // ---- wait for fps to publish this chunk's 32 centers.
      // RELAXED poll: agent-scope atomic load reads the L3 coherence point,
      // no buffer_inv (R28 fix). Seeing prog>=need implies idx is in L3.
      const int need = gc * 32 + 32;
      for (;;) {
        if (t == 0) *sprog = __hip_atomic_load(prog, __ATOMIC_RELAXED, __HIP_MEMORY_SCOPE_AGENT);
        __syncthreads();
        if (*sprog >= need) break;
        __builtin_amdgcn_s_sleep(32);
        __syncthreads();
      }
      // ---- kNN (R25 body): 32 centers x 32 splits
      const int sp = t >> 5;
      const int cl = t & 31;
      const int i = gc * 32 + cl;
      // agent-scope relaxed atomic: reads the L3 coherence point directly
      const int ci = __hip_atomic_load(idx + i, __ATOMIC_RELAXED, __HIP_MEMORY_SCOPE_AGENT);
      const float cx = __builtin_nontemporal_load(&pos[3 * ci]);
      const float cy = __builtin_nontemporal_load(&pos[3 * ci + 1]);
      const float cz = __builtin_nontemporal_load(&pos[3 * ci + 2]);
      float nd[NB]; int ni[NB];
#pragma unroll
      for (int q = 0; q < NB; ++q) { nd[q] = 3.402823466e38f; ni[q] = 0x7fffffff; }

      for (int base = 0; base < N_PTS; base += KTILE) {
        __syncthreads();
        for (int j = t; j < KTILE; j += 1024) {
          int pnt = base + j;
          // non-temporal: this is the 48 MB worker stream that was evicting
          // fps's hot xs lines from the shared XCD L2.
          float px = __builtin_nontemporal_load(&pos[3 * pnt]);
          float py = __builtin_nontemporal_load(&pos[3 * pnt + 1]);
          float pz = __builtin_nontemporal_load(&pos[3 * pnt + 2]);
          s_p[j] = make_float4(px, py, pz, 0.f);
        }
        __syncthreads();
        for (int j = sp; j < KTILE; j += KNS) {
          float4 q4 = s_p[j];
          float dx = __fsub_rn(cx, q4.x);
          float dy = __fsub_rn(cy, q4.y);
          float dz = __fsub_rn(cz, q4.z);
          float d2 = __fadd_rn(__fadd_rn(__fmul_rn(dx, dx), __fmul_rn(dy, dy)), __fmul_rn(dz, dz));
          if (d2 < nd[NB - 1]) {
            float cd = d2; int cp = base + j;
#pragma unroll
            for (int q = 0; q < NB; ++q) {
              bool sw = (cd < nd[q]) || (cd == nd[q] && cp < ni[q]);
              if (sw) { float td = nd[q]; int tp = ni[q]; nd[q] = cd; ni[q] = cp; cd = td; cp = tp; }
            }
          }
        }
      }
#pragma unroll
      for (int q = 0; q < NB; ++q) { spd[cl][sp * NB + q] = nd[q]; spi[cl][sp * NB + q] = ni[q]; }
      __syncthreads();
      if (sp == 0) {
        int cur[KNS];
#pragma unroll
        for (int s = 0; s < KNS; ++s) cur[s] = 0;
        int vb = 0;
        for (int q = 0; q < NB; ++q) {
          float bd = 3.402823466e38f; int bi = 0x7fffffff; int bsl = 0;
#pragma unroll
          for (int s = 0; s < KNS; ++s) {
            float d = spd[cl][s * NB + cur[s]]; int id = spi[cl][s * NB + cur[s]];
            if (d < bd || (d == bd && id < bi)) { bd = d; bi = id; bsl = s; }
          }
#pragma unroll
          for (int s = 0; s < KNS; ++s) cur[s] += (s == bsl) ? 1 : 0;
          src[i * NB + q] = bi;
          if (bd <= R2) vb |= (1 << q);
        }
        valid[i] = vb;
      }
      __syncthreads();

      // ---- MLP (R26 math, kk-ascending fmaf): 4 rounds x 8 centers x 128 ch
      for (int r = 0; r < 4; ++r) {
        const int c8 = t >> 7;          // 0..7
        const int ch = t & 127;
        const int im = gc * 32 + r * 8 + c8;
        if (ch < NB) {
          int s = src[im * NB + ch];
          // reference subtracts pos[:s] row im, NOT the sampled center
          float sx0 = __builtin_nontemporal_load(&pos[3 * s + 0]);
          float sx1 = __builtin_nontemporal_load(&pos[3 * s + 1]);
          float sx2 = __builtin_nontemporal_load(&pos[3 * s + 2]);
          float ix0 = __builtin_nontemporal_load(&pos[3 * im + 0]);
          float ix1 = __builtin_nontemporal_load(&pos[3 * im + 1]);
          float ix2 = __builtin_nontemporal_load(&pos[3 * im + 2]);
          msrel[(c8 * NB + ch) * 3 + 0] = sx0 - ix0;
          msrel[(c8 * NB + ch) * 3 + 1] = sx1 - ix1;
          msrel[(c8 * NB + ch) * 3 + 2] = sx2 - ix2;
        }
        __syncthreads();
        for (int e = t; e < 8 * NB * CHID; e += 1024) {
          int kk = e & 63;
          int n = (e >> 6) % NB;
          int cc = e / (NB * CHID);
          float a = sb1[kk] + msrel[(cc * NB + n) * 3 + 0] * sW1[kk]
                            + msrel[(cc * NB + n) * 3 + 1] * sW1[64 + kk]
                            + msrel[(cc * NB + n) * 3 + 2] * sW1[128 + kk];
          msh1[(cc * NB + n) * CHID + kk] = fmaxf(a, 0.0f);
        }
        __syncthreads();
        {
          const int vmask = valid[im];
          const float bb = b2[ch];
          float m = 0.0f;
          bool any = false;
          for (int n = 0; n < NB; ++n) {
            if (vmask & (1 << n)) {
              float acc = bb;
#pragma unroll
              for (int g = 0; g < 16; ++g) {
                float4 h = *(const float4*)&msh1[(c8 * NB + n) * CHID + 4 * g];
                float4 w = *(const float4*)&sW2T[ch * W2S + 4 * g];
                acc = fmaf(h.x, w.x, acc);
                acc = fmaf(h.y, w.y, acc);
                acc = fmaf(h.z, w.z, acc);
                acc = fmaf(h.w, w.w, acc);
              }
              m = any ? fmaxf(m, acc) : acc;
              any = true;
            }
          }
          // non-temporal: out is write-only, never re-read.
          __builtin_nontemporal_store(any ? m : 0.0f, &out[(size_t)im * COUT + ch]);
        }
        __syncthreads();
      }
    }
  }
}

// ======================= launch =======================
extern "C" void kernel_launch(void* const* d_in, const int* in_sizes, int n_in,
                              void* d_out, int out_size, void* d_ws, size_t ws_size,
                              hipStream_t stream) {
  (void)in_sizes; (void)n_in; (void)out_size; (void)ws_size;
  const float* pos = (const float*)d_in[0];
  const float* W1 = (const float*)d_in[2];
  const float* b1 = (const float*)d_in[3];
  const float* W2 = (const float*)d_in[4];
  const float* b2 = (const float*)d_in[5];
  float* out = (float*)d_out;

  char* ws = (char*)d_ws;
  int*   idx   = (int*)ws;                 ws += (size_t)N_S * 4;          // 32 KB
  int*   src   = (int*)ws;                 ws += (size_t)N_S * NB * 4;     // 320 KB
  int*   valid = (int*)ws;                 ws += (size_t)N_S * 4;          // 32 KB
  float* xs    = (float*)ws;               ws += (size_t)N_PTS * 4;        // 64 KB
  float* ys    = (float*)ws;               ws += (size_t)N_PTS * 4;
  float* zs    = (float*)ws;               ws += (size_t)N_PTS * 4;
  int*   oid   = (int*)ws;                 ws += (size_t)N_PTS * 4;
  int*   progp = (int*)ws;                 ws += 16;                       // progress counter
  // sort temporaries alias the src region (sort completes before knn writes src)
  int* cellid = src;                 // N_PTS ints = 64 KB  (src region is 320 KB)
  int* hist   = src + N_PTS;         // NCELL ints = 16 KB
  int* basebuf= src + N_PTS + NCELL; // NCELL ints = 16 KB

  (void)hipMemsetAsync(hist, 0, (size_t)NCELL * 4, stream);
  (void)hipMemsetAsync(progp, 0, 4, stream);
  cell_kernel<<<N_PTS / 256, 256, 0, stream>>>(pos, cellid, hist);
  scan_kernel<<<1, 1024, 0, stream>>>(hist, basebuf);
  scatter_kernel<<<N_PTS / 256, 256, 0, stream>>>(pos, cellid, basebuf, xs, ys, zs, oid);
  fused_kernel<<<1 + WRK, 1024, 0, stream>>>(pos, xs, ys, zs, oid, idx, src, valid,
                                             W1, b1, W2, b2, out, progp);
}

// Round 16
// 6564.487 us; speedup vs baseline: 1.0767x; 1.0767x over previous
//
#include <hip/hip_runtime.h>

typedef unsigned int u32;
typedef unsigned long long u64;
typedef float f32x2 __attribute__((ext_vector_type(2)));

#define N_PTS 16384
#define N_S   8192
#define NB    10
#define CHID  64
#define COUT  128
#define R2    0.0625f
#define NCELL 4096

// ======================= sort: morton counting sort =======================
__device__ __forceinline__ u32 spread3(u32 v) {  // 4 bits -> every 3rd bit
  return (v & 1u) | ((v & 2u) << 2) | ((v & 4u) << 4) | ((v & 8u) << 6);
}

__global__ void cell_kernel(const float* __restrict__ pos, int* __restrict__ cellid,
                            int* __restrict__ hist) {
  int i = blockIdx.x * 256 + threadIdx.x;
  float x = pos[3 * i], y = pos[3 * i + 1], z = pos[3 * i + 2];
  u32 ix = (u32)(x * 16.0f); if (ix > 15u) ix = 15u;
  u32 iy = (u32)(y * 16.0f); if (iy > 15u) iy = 15u;
  u32 iz = (u32)(z * 16.0f); if (iz > 15u) iz = 15u;
  u32 c = spread3(ix) | (spread3(iy) << 1) | (spread3(iz) << 2);
  cellid[i] = (int)c;
  atomicAdd(&hist[c], 1);
}

__global__ __launch_bounds__(1024) void scan_kernel(const int* __restrict__ hist,
                                                    int* __restrict__ base) {
  __shared__ int sp[1024];
  int t = threadIdx.x;
  int h0 = hist[4 * t], h1 = hist[4 * t + 1], h2 = hist[4 * t + 2], h3 = hist[4 * t + 3];
  int s = h0 + h1 + h2 + h3;
  int acc = s;
  sp[t] = s;
  __syncthreads();
  for (int off = 1; off < 1024; off <<= 1) {
    int v = (t >= off) ? sp[t - off] : 0;
    __syncthreads();
    acc += v;
    sp[t] = acc;
    __syncthreads();
  }
  int excl = acc - s;
  base[4 * t + 0] = excl;
  base[4 * t + 1] = excl + h0;
  base[4 * t + 2] = excl + h0 + h1;
  base[4 * t + 3] = excl + h0 + h1 + h2;
}

__global__ void scatter_kernel(const float* __restrict__ pos, const int* __restrict__ cellid,
                               int* __restrict__ base, float* __restrict__ xs,
                               float* __restrict__ ys, float* __restrict__ zs,
                               int* __restrict__ oid) {
  int i = blockIdx.x * 256 + threadIdx.x;
  int c = cellid[i];
  int d = atomicAdd(&base[c], 1);
  xs[d] = pos[3 * i]; ys[d] = pos[3 * i + 1]; zs[d] = pos[3 * i + 2];
  oid[d] = i;
}

// ======================= fused FPS + kNN + MLP =======================
// R30 (resubmit; R15 bench was an infra failure -- container acquire, kernel
// never ran; audit found no hang/correctness defect: uniform barriers, prog
// covers need=8192, unique merge keys, LDS fits, 193 blocks co-resident).
// R29 post-mortem: NT hints REGRESSED (+160us) and falsified the contention
// theory. Correct accounting of R28's 6870: fps-in-fusion ~6600 (unchanged
// from standalone!) + ~270us TAIL = the last chunk (available only at fps
// completion) processed by ONE block at ~270us. R29's NT loads slowed the
// workers' chunk time 270->~430 -> tail grew by the observed +160.
// R30: revert ALL R29 changes (exact R28 protocol: plain idx stores +
// RELEASE prog publish + RELAXED agent polls). Halve the tail:
//  - chunks of 16 centers, ONE WAVE PER CENTER: lane l scans points
//    l, l+64, ... (64 splits x 256 pts = half the per-thread work ->
//    chunk ~135us), top-10 kept in registers.
//  - merge = 10 rounds of in-wave dpp max-reduce on order-reversed key
//    ((0x7F800000 - dbits)<<32)|(16383-idx): high word is a positive finite
//    double for ALL dbits<=FLT_MAX (transform in [1,0x7F800000], exp<=0x7F8)
//    -> max(transform) == lex-min (d, idx); dpp shift-in 0 = max identity
//    (the PROVEN fps reduce machinery). Winner lane pops via static unrolled
//    shift. spd/spi LDS merge (82 KB) deleted.
//  - prog cadence 32->16 iters (same release protocol, 2x freq, trivial).
#define FPS_T 1024
#define PPT   16
#define WRK   192          // worker blocks
#define CHC   16           // centers per chunk (one wave each)
#define NCHK  (N_S / CHC)  // 512 chunks

// LDS union layout (bytes):
//  fps   : s_yz [0,131072) | s_k [131072,131328)
//  worker: s_p [0,16384) | sW2T [16384,51200) | sW1 [51200,51968)
//          | sb1 [51968,52224) | sprog [52224,52228)
//          | msh1 [53248,73728) | msrel [73728,74688)
#define OFF_SK    131072
#define OFF_W2T   16384
#define OFF_W1    51200
#define OFF_B1    51968
#define OFF_PROG  52224
#define OFF_MSH1  53248
#define OFF_MSREL 73728
#define SMEM_SZ   131328

#define KTILE  1024
#define W2S    68    // W2T stride: 16B-aligned (68*4=272=17*16), bank-swept

#define PT_LIST(OP) OP(0) OP(1) OP(2) OP(3) OP(4) OP(5) OP(6) OP(7) \
                    OP(8) OP(9) OP(10) OP(11) OP(12) OP(13) OP(14) OP(15)
#define G4_LIST(OP) OP(0,0,1,2,3,0,1)   OP(1,4,5,6,7,2,3) \
                    OP(2,8,9,10,11,4,5) OP(3,12,13,14,15,6,7)
#define PR_LIST(OP) OP(0) OP(1) OP(2) OP(3) OP(4) OP(5) OP(6) OP(7)

// u64 max via positive-double max (key high word = finite positive float-ish
// bits, exp field never all-ones, sign 0; positive doubles order == bit order).
__device__ __forceinline__ u64 u64fmax(u64 a, u64 b) {
  double ad = __longlong_as_double((long long)a);
  double bd = __longlong_as_double((long long)b);
  return (u64)(long long)__double_as_longlong(fmax(ad, bd));
}

template <int CTRL, int RM>
__device__ __forceinline__ u64 dppmax(u64 cur) {
  int slo = __builtin_amdgcn_update_dpp(0, (int)(u32)cur, CTRL, RM, 0xf, false);
  int shi = __builtin_amdgcn_update_dpp(0, (int)(u32)(cur >> 32), CTRL, RM, 0xf, false);
  u64 o = ((u64)(u32)shi << 32) | (u32)slo;
  return u64fmax(o, cur);
}

// full-wave max -> lane 63, then broadcast via readlane (uniform result)
__device__ __forceinline__ u64 wavemax_bcast(u64 x) {
  x = dppmax<0x111, 0xf>(x);   // row_shr:1
  x = dppmax<0x112, 0xf>(x);   // row_shr:2
  x = dppmax<0x114, 0xf>(x);   // row_shr:4
  x = dppmax<0x118, 0xf>(x);   // row_shr:8
  x = dppmax<0x142, 0xa>(x);   // row_bcast:15 -> rows 1,3
  x = dppmax<0x143, 0xc>(x);   // row_bcast:31 -> rows 2,3
  u32 lo = (u32)__builtin_amdgcn_readlane((int)(u32)x, 63);
  u32 hi = (u32)__builtin_amdgcn_readlane((int)(u32)(x >> 32), 63);
  return ((u64)hi << 32) | lo;
}

// packed 2xf32 ops (VOP3P). IEEE RNE per element, no contraction (opaque asm).
__device__ __forceinline__ f32x2 pk_add(f32x2 a, f32x2 b) {
  f32x2 d;
  asm("v_pk_add_f32 %0, %1, %2" : "=v"(d) : "v"(a), "v"(b));
  return d;
}
__device__ __forceinline__ f32x2 pk_mul(f32x2 a, f32x2 b) {
  f32x2 d;
  asm("v_pk_mul_f32 %0, %1, %2" : "=v"(d) : "v"(a), "v"(b));
  return d;
}

// merge key: max-order == lex-min (d, idx). dbits <= 0x7F7FFFFF ->
// high word in [1, 0x7F800000], positive finite double. idx <= 16383.
__device__ __forceinline__ u64 mkey(float d, int idx) {
  return ((u64)(0x7F800000u - __float_as_uint(d)) << 32) | (u32)(16383 - idx);
}

__global__ __launch_bounds__(1024, 4)
void fused_kernel(const float* __restrict__ pos,
                  const float* __restrict__ xs,
                  const float* __restrict__ ys,
                  const float* __restrict__ zs,
                  const int* __restrict__ oidv,
                  int* __restrict__ idx,
                  int* __restrict__ src,
                  int* __restrict__ valid,
                  const float* __restrict__ W1,
                  const float* __restrict__ b1,
                  const float* __restrict__ W2,
                  const float* __restrict__ b2,
                  float* __restrict__ out,
                  int* __restrict__ prog) {
  __shared__ __align__(16) unsigned char smem[SMEM_SZ];
  const int t = threadIdx.x;

  if (blockIdx.x == 0) {
    // =================== FPS (R24 body, frozen; + prog publish) ===================
    float2* s_yz = (float2*)smem;
    u64 (*s_k)[16] = (u64 (*)[16])(smem + OFF_SK);
    const int wv = t >> 6;
    const int base0 = t * PPT;
    const float4* __restrict__ xv = (const float4*)(xs + base0);
    const float4* __restrict__ yv = (const float4*)(ys + base0);
    const float4* __restrict__ zv = (const float4*)(zs + base0);
    const int4*   __restrict__ ov = (const int4*)(oidv + base0);

#define DECLP(J) float md##J;
    PT_LIST(DECLP)
#undef DECLP
#define DECLC(J) u32 C##J;
    PT_LIST(DECLC)
#undef DECLC
#define DECLX(P) f32x2 X##P; f32x2 Y##P; f32x2 Z##P;
    PR_LIST(DECLX)
#undef DECLX

    float bnx = 3.4e38f, bxx = -3.4e38f, bny = 3.4e38f, bxy = -3.4e38f,
          bnz = 3.4e38f, bxz = -3.4e38f;

#define INIT4(G, J0, J1, J2, J3, PA, PB) { \
    float4 vx = xv[G], vy = yv[G], vz = zv[G]; int4 vo = ov[G]; \
    md##J0 = 3.402823466e38f; md##J1 = 3.402823466e38f; \
    md##J2 = 3.402823466e38f; md##J3 = 3.402823466e38f; \
    X##PA.x = vx.x; X##PA.y = vx.y; X##PB.x = vx.z; X##PB.y = vx.w; \
    Y##PA.x = vy.x; Y##PA.y = vy.y; Y##PB.x = vy.z; Y##PB.y = vy.w; \
    Z##PA.x = vz.x; Z##PA.y = vz.y; Z##PB.x = vz.z; Z##PB.y = vz.w; \
    s_yz[J0 * FPS_T + t] = make_float2(vy.x, vz.x); \
    s_yz[J1 * FPS_T + t] = make_float2(vy.y, vz.y); \
    s_yz[J2 * FPS_T + t] = make_float2(vy.z, vz.z); \
    s_yz[J3 * FPS_T + t] = make_float2(vy.w, vz.w); \
    C##J0 = ((16383u - (u32)vo.x) << 14) | (u32)(base0 + J0); \
    C##J1 = ((16383u - (u32)vo.y) << 14) | (u32)(base0 + J1); \
    C##J2 = ((16383u - (u32)vo.z) << 14) | (u32)(base0 + J2); \
    C##J3 = ((16383u - (u32)vo.w) << 14) | (u32)(base0 + J3); \
    bnx = fminf(bnx, fminf(fminf(vx.x, vx.y), fminf(vx.z, vx.w))); \
    bxx = fmaxf(bxx, fmaxf(fmaxf(vx.x, vx.y), fmaxf(vx.z, vx.w))); \
    bny = fminf(bny, fminf(fminf(vy.x, vy.y), fminf(vy.z, vy.w))); \
    bxy = fmaxf(bxy, fmaxf(fmaxf(vy.x, vy.y), fmaxf(vy.z, vy.w))); \
    bnz = fminf(bnz, fminf(fminf(vz.x, vz.y), fminf(vz.z, vz.w))); \
    bxz = fmaxf(bxz, fmaxf(fmaxf(vz.x, vz.y), fmaxf(vz.z, vz.w))); }
    G4_LIST(INIT4)
#undef INIT4

    // key = md_bits<<32 | (16383-oid)<<14 | sidx. Lex max == numpy argmax.
    u64 ckey = 0;
    u64 wklast = 0;
    float cmaxf = 3.402823466e38f;
    float cx = pos[0], cy = pos[1], cz = pos[2];
    if (t == 0) idx[0] = 0;
    __syncthreads();

    for (int k = 0; k < N_S - 1; ++k) {
      float dxl = fmaxf(fmaxf(bnx - cx, cx - bxx), 0.0f);
      float dyl = fmaxf(fmaxf(bny - cy, cy - bxy), 0.0f);
      float dzl = fmaxf(fmaxf(bnz - cz, cz - bxz), 0.0f);
      float lb2 = dxl * dxl + dyl * dyl + dzl * dzl;
      bool act = (0.99f * lb2 < cmaxf);

      if (__ballot(act)) {
        if (act) {
          f32x2 ncx2; ncx2.x = -cx; ncx2.y = -cx;
          f32x2 ncy2; ncy2.x = -cy; ncy2.y = -cy;
          f32x2 ncz2; ncz2.x = -cz; ncz2.y = -cz;
          u64 bkA = 0, bkB = 0;
#define UPDP(P, J0, J1) { \
          f32x2 dx2 = pk_add(X##P, ncx2); \
          f32x2 dy2 = pk_add(Y##P, ncy2); \
          f32x2 dz2 = pk_add(Z##P, ncz2); \
          f32x2 sq = pk_add(pk_mul(dx2, dx2), pk_mul(dy2, dy2)); \
          f32x2 d2 = pk_add(sq, pk_mul(dz2, dz2)); \
          float m0 = fminf(md##J0, d2.x); md##J0 = m0; \
          bkA = u64fmax(bkA, ((u64)__float_as_uint(m0) << 32) | C##J0); \
          float m1 = fminf(md##J1, d2.y); md##J1 = m1; \
          bkB = u64fmax(bkB, ((u64)__float_as_uint(m1) << 32) | C##J1); }
          UPDP(0, 0, 1)  UPDP(1, 2, 3)  UPDP(2, 4, 5)  UPDP(3, 6, 7)
          UPDP(4, 8, 9)  UPDP(5, 10, 11) UPDP(6, 12, 13) UPDP(7, 14, 15)
#undef UPDP
          ckey = u64fmax(bkA, bkB);
          cmaxf = __uint_as_float((u32)(ckey >> 32));
        }
        u64 wk = ckey;
        wk = dppmax<0x111, 0xf>(wk);   // row_shr:1
        wk = dppmax<0x112, 0xf>(wk);   // row_shr:2
        wk = dppmax<0x114, 0xf>(wk);   // row_shr:4
        wk = dppmax<0x118, 0xf>(wk);   // row_shr:8
        wk = dppmax<0x142, 0xa>(wk);   // row_bcast:15 -> rows 1,3
        wk = dppmax<0x143, 0xc>(wk);   // row_bcast:31 -> rows 2,3
        wklast = wk;
      }
      if ((t & 63) == 63) s_k[k & 1][wv] = wklast;
      __syncthreads();

      u64 gk = s_k[k & 1][t & 15];
      gk = dppmax<0x121, 0xf>(gk);   // row_ror:1
      gk = dppmax<0x122, 0xf>(gk);   // row_ror:2
      gk = dppmax<0x124, 0xf>(gk);   // row_ror:4
      gk = dppmax<0x128, 0xf>(gk);   // row_ror:8
      u32 glo = (u32)__builtin_amdgcn_readfirstlane((int)(u32)gk);
      u32 ghi = (u32)__builtin_amdgcn_readfirstlane((int)(u32)(gk >> 32));
      u64 gmax = ((u64)ghi << 32) | glo;
      int sidx = (int)(gmax & 16383u);
      if (t == 0) {
        idx[k + 1] = 16383 - (int)((gmax >> 14) & 16383u);
        // publish at chunk boundaries (k+2 multiple of 16): RELEASE emits
        // wbl2 (writeback, no invalidate) -> idx reaches L3 before the
        // counter store; fps's clean L2 lines stay resident.
        if ((k & 15) == 14)
          __hip_atomic_store(prog, k + 2, __ATOMIC_RELEASE, __HIP_MEMORY_SCOPE_AGENT);
      }
      int cell = (sidx & (PPT - 1)) * FPS_T + (sidx >> 4);
      cx = xs[sidx];
      float2 yz = s_yz[cell];
      cy = yz.x;
      cz = yz.y;
    }
  } else {
    // =================== worker: kNN + MLP per ready chunk ===================
    const int wid = blockIdx.x - 1;   // 0..WRK-1
    float4* s_p  = (float4*)smem;
    float* sW2T  = (float*)(smem + OFF_W2T);
    float* sW1   = (float*)(smem + OFF_W1);
    float* sb1   = (float*)(smem + OFF_B1);
    int*   sprog = (int*)(smem + OFF_PROG);
    float* msh1  = (float*)(smem + OFF_MSH1);   // [8][NB][CHID]
    float* msrel = (float*)(smem + OFF_MSREL);  // [8][NB][3]

    // stage W2 transposed + W1 + b1; zero a tail-row slice (overlapped with fps)
    for (int e = t; e < CHID * COUT; e += 1024) {
      int kk = e >> 7, c = e & (COUT - 1);
      sW2T[c * W2S + kk] = W2[e];
    }
    if (t < 3 * CHID) sW1[t] = W1[t];
    if (t < CHID) sb1[t] = b1[t];
    {
      float4* outv = (float4*)(out + (size_t)N_S * COUT);
      const int cnt = (N_PTS - N_S) * COUT / 4;
      for (int j = wid * 1024 + t; j < cnt; j += WRK * 1024)
        outv[j] = make_float4(0.f, 0.f, 0.f, 0.f);
    }
    __syncthreads();

    for (int gc = wid; gc < NCHK; gc += WRK) {
      // ---- wait for fps to publish this chunk's CHC centers (R28 protocol:
      // relaxed agent poll, no buffer_inv; prog>=need implies idx in L3)
      const int need = gc * CHC + CHC;
      for (;;) {
        if (t == 0) *sprog = __hip_atomic_load(prog, __ATOMIC_RELAXED, __HIP_MEMORY_SCOPE_AGENT);
        __syncthreads();
        if (*sprog >= need) break;
        __builtin_amdgcn_s_sleep(32);
        __syncthreads();
      }
      // ---- kNN: one WAVE per center; lane l = split l (points l, l+64, ...)
      const int w = t >> 6;            // wave 0..15 -> center
      const int l = t & 63;            // lane = split
      const int i = gc * CHC + w;
      const int ci = __hip_atomic_load(idx + i, __ATOMIC_RELAXED, __HIP_MEMORY_SCOPE_AGENT);
      const float cx = pos[3 * ci], cy = pos[3 * ci + 1], cz = pos[3 * ci + 2];
      float nd[NB]; int ni[NB];
#pragma unroll
      for (int q = 0; q < NB; ++q) { nd[q] = 3.402823466e38f; ni[q] = 16383; }

      for (int base = 0; base < N_PTS; base += KTILE) {
        __syncthreads();
        {
          int pnt = base + t;
          s_p[t] = make_float4(pos[3 * pnt], pos[3 * pnt + 1], pos[3 * pnt + 2], 0.f);
        }
        __syncthreads();
        for (int j = l; j < KTILE; j += 64) {
          float4 q4 = s_p[j];
          float dx = __fsub_rn(cx, q4.x);
          float dy = __fsub_rn(cy, q4.y);
          float dz = __fsub_rn(cz, q4.z);
          float d2 = __fadd_rn(__fadd_rn(__fmul_rn(dx, dx), __fmul_rn(dy, dy)), __fmul_rn(dz, dz));
          if (d2 < nd[NB - 1]) {
            float cd = d2; int cp = base + j;
#pragma unroll
            for (int q = 0; q < NB; ++q) {
              bool sw = (cd < nd[q]) || (cd == nd[q] && cp < ni[q]);
              if (sw) { float td = nd[q]; int tp = ni[q]; nd[q] = cd; ni[q] = cp; cd = td; cp = tp; }
            }
          }
        }
      }
      // ---- in-wave 64-list merge: 10 rounds of wave-max on reversed keys.
      // Winner lane pops its head via static unrolled shift. Keys are unique
      // (each point in exactly one lane's split); sentinels never win while
      // real entries remain (640 real entries >= 10 rounds).
      {
        int vb = 0;
        u64 myk = mkey(nd[0], ni[0]);
        for (int q = 0; q < NB; ++q) {
          u64 g = wavemax_bcast(myk);
          if (myk == g) {
#pragma unroll
            for (int j = 0; j < NB - 1; ++j) { nd[j] = nd[j + 1]; ni[j] = ni[j + 1]; }
            nd[NB - 1] = 3.402823466e38f; ni[NB - 1] = 16383;
            myk = mkey(nd[0], ni[0]);
          }
          if (l == 0) {
            src[i * NB + q] = 16383 - (int)(g & 0xFFFFFFFFu);
            float bd = __uint_as_float(0x7F800000u - (u32)(g >> 32));
            if (bd <= R2) vb |= (1 << q);
          }
        }
        if (l == 0) valid[i] = vb;
      }
      __syncthreads();

      // ---- MLP (R26 math, kk-ascending fmaf): 2 rounds x 8 centers x 128 ch
      for (int r = 0; r < 2; ++r) {
        const int c8 = t >> 7;          // 0..7
        const int ch = t & 127;
        const int im = gc * CHC + r * 8 + c8;
        if (ch < NB) {
          int s = src[im * NB + ch];
          // reference subtracts pos[:s] row im, NOT the sampled center
          msrel[(c8 * NB + ch) * 3 + 0] = pos[3 * s + 0] - pos[3 * im + 0];
          msrel[(c8 * NB + ch) * 3 + 1] = pos[3 * s + 1] - pos[3 * im + 1];
          msrel[(c8 * NB + ch) * 3 + 2] = pos[3 * s + 2] - pos[3 * im + 2];
        }
        __syncthreads();
        for (int e = t; e < 8 * NB * CHID; e += 1024) {
          int kk = e & 63;
          int n = (e >> 6) % NB;
          int cc = e / (NB * CHID);
          float a = sb1[kk] + msrel[(cc * NB + n) * 3 + 0] * sW1[kk]
                            + msrel[(cc * NB + n) * 3 + 1] * sW1[64 + kk]
                            + msrel[(cc * NB + n) * 3 + 2] * sW1[128 + kk];
          msh1[(cc * NB + n) * CHID + kk] = fmaxf(a, 0.0f);
        }
        __syncthreads();
        {
          const int vmask = valid[im];
          const float bb = b2[ch];
          float m = 0.0f;
          bool any = false;
          for (int n = 0; n < NB; ++n) {
            if (vmask & (1 << n)) {
              float acc = bb;
#pragma unroll
              for (int g = 0; g < 16; ++g) {
                float4 h = *(const float4*)&msh1[(c8 * NB + n) * CHID + 4 * g];
                float4 wv4 = *(const float4*)&sW2T[ch * W2S + 4 * g];
                acc = fmaf(h.x, wv4.x, acc);
                acc = fmaf(h.y, wv4.y, acc);
                acc = fmaf(h.z, wv4.z, acc);
                acc = fmaf(h.w, wv4.w, acc);
              }
              m = any ? fmaxf(m, acc) : acc;
              any = true;
            }
          }
          out[(size_t)im * COUT + ch] = any ? m : 0.0f;
        }
        __syncthreads();
      }
    }
  }
}

// ======================= launch =======================
extern "C" void kernel_launch(void* const* d_in, const int* in_sizes, int n_in,
                              void* d_out, int out_size, void* d_ws, size_t ws_size,
                              hipStream_t stream) {
  (void)in_sizes; (void)n_in; (void)out_size; (void)ws_size;
  const float* pos = (const float*)d_in[0];
  const float* W1 = (const float*)d_in[2];
  const float* b1 = (const float*)d_in[3];
  const float* W2 = (const float*)d_in[4];
  const float* b2 = (const float*)d_in[5];
  float* out = (float*)d_out;

  char* ws = (char*)d_ws;
  int*   idx   = (int*)ws;                 ws += (size_t)N_S * 4;          // 32 KB
  int*   src   = (int*)ws;                 ws += (size_t)N_S * NB * 4;     // 320 KB
  int*   valid = (int*)ws;                 ws += (size_t)N_S * 4;          // 32 KB
  float* xs    = (float*)ws;               ws += (size_t)N_PTS * 4;        // 64 KB
  float* ys    = (float*)ws;               ws += (size_t)N_PTS * 4;
  float* zs    = (float*)ws;               ws += (size_t)N_PTS * 4;
  int*   oid   = (int*)ws;                 ws += (size_t)N_PTS * 4;
  int*   progp = (int*)ws;                 ws += 16;                       // progress counter
  // sort temporaries alias the src region (sort completes before knn writes src)
  int* cellid = src;                 // N_PTS ints = 64 KB  (src region is 320 KB)
  int* hist   = src + N_PTS;         // NCELL ints = 16 KB
  int* basebuf= src + N_PTS + NCELL; // NCELL ints = 16 KB

  (void)hipMemsetAsync(hist, 0, (size_t)NCELL * 4, stream);
  (void)hipMemsetAsync(progp, 0, 4, stream);
  cell_kernel<<<N_PTS / 256, 256, 0, stream>>>(pos, cellid, hist);
  scan_kernel<<<1, 1024, 0, stream>>>(hist, basebuf);
  scatter_kernel<<<N_PTS / 256, 256, 0, stream>>>(pos, cellid, basebuf, xs, ys, zs, oid);
  fused_kernel<<<1 + WRK, 1024, 0, stream>>>(pos, xs, ys, zs, oid, idx, src, valid,
                                             W1, b1, W2, b2, out, progp);
}